// Round 2
// baseline (2333.223 us; speedup 1.0000x reference)
//
#include <hip/hip_runtime.h>

// LightGCN: out = 0.25*(e0 + S e0 + S^2 e0 + S^3 e0), S = 10M-nnz COO, N=500k, EMB=64.
// R4: bucket scatter (3907 cursors) + per-bucket LDS counting sort -> row-grouped pairs
//     + 3x register-accumulating SpMM. Measured 2572.6 us.
// R5: spmm_fused restructured from 1 row/wave (64 lanes x f32) to 4 rows/wave
//     (16 lanes x float4). Theory: spmm is latency-bound on the dependent
//     pairs->Z gather chain; 4 rows/wave gives 4x gathers in flight per VMEM
//     instruction and 4x fewer waves. Pairs stream (80MB x3, read-once-per-layer)
//     nontemporal so it doesn't evict the L3-resident Z/W tables (~464MB > 256MB L3).
// R6: fix compile — __builtin_nontemporal_load can't take uint2*; load the 8-byte
//     pair as unsigned long long (legal) and unpack.
// Horner ping-pong (Z in ws, W = d_out):
//   Z=e0; L1: W = e0 + S Z; L2: Z = e0 + S W; L3: out = 0.25*(e0 + S Z).

#define NUSERS 100000
#define NNODES 500000
#define EMB 64
#define RPB 128                                   // rows per bucket
#define NBUCKETS ((NNODES + RPB - 1) / RPB)       // 3907
#define COLBITS 19
#define CMASK ((1u << COLBITS) - 1u)
#define SORT_CAP 6016                             // pairs stageable in LDS (47KB); mean=2560
#define SLACK_PAIRS 131072                        // overflow region (never hit for random rows)

// ---------------- preprocessing ----------------

__global__ void hist_bucket(const int* __restrict__ rows, int nnz,
                            int* __restrict__ counts) {
  __shared__ int h[NBUCKETS];
  for (int i = threadIdx.x; i < NBUCKETS; i += blockDim.x) h[i] = 0;
  __syncthreads();
  int i = blockIdx.x * blockDim.x + threadIdx.x;
  int stride = gridDim.x * blockDim.x;
  for (; i < nnz; i += stride) atomicAdd(&h[rows[i] >> 7], 1);
  __syncthreads();
  for (int j = threadIdx.x; j < NBUCKETS; j += blockDim.x)
    if (h[j]) atomicAdd(&counts[j], h[j]);
}

// Single-block exclusive scan of counts[n] (n <= 4096), 512 threads x 8.
__global__ void scan_buckets(const int* __restrict__ counts,
                             int* __restrict__ bptr, int* __restrict__ cursor,
                             int n, int nnz) {
  __shared__ int s[512];
  const int t = threadIdx.x;
  const int base = t * 8;
  int e[8];
  int tsum = 0;
#pragma unroll
  for (int j = 0; j < 8; ++j) {
    e[j] = (base + j < n) ? counts[base + j] : 0;
    tsum += e[j];
  }
  s[t] = tsum;
  __syncthreads();
  for (int off = 1; off < 512; off <<= 1) {
    int v = (t >= off) ? s[t - off] : 0;
    __syncthreads();
    s[t] += v;
    __syncthreads();
  }
  int run = s[t] - tsum;
#pragma unroll
  for (int j = 0; j < 8; ++j) {
    if (base + j < n) { bptr[base + j] = run; cursor[base + j] = run; }
    run += e[j];
  }
  if (t == 511) bptr[n] = nnz;
}

// Scatter (row,col,val) -> bucketed pairs. key = (row&127)<<19 | col.
__global__ void scatter_bucket(const int* __restrict__ rows,
                               const int* __restrict__ cols,
                               const float* __restrict__ vals, int nnz,
                               int* __restrict__ cursor,
                               uint2* __restrict__ pairs) {
  int i = blockIdx.x * blockDim.x + threadIdx.x;
  int stride = gridDim.x * blockDim.x;
  for (; i < nnz; i += stride) {
    int r = rows[i];
    unsigned key = ((unsigned)(r & (RPB - 1)) << COLBITS) | (unsigned)cols[i];
    int pos = atomicAdd(&cursor[r >> 7], 1);
    pairs[pos] = make_uint2(key, __float_as_uint(vals[i]));
  }
}

// Per-bucket LDS counting sort: group pairs by row (in place), strip row bits,
// emit per-row [rs, re) into the pairs array. Overflow (>SORT_CAP) goes to slack.
__global__ __launch_bounds__(256) void sort_bucket(
    const int* __restrict__ bptr, uint2* __restrict__ pairs,
    int* __restrict__ rs, int* __restrict__ re,
    int* __restrict__ ovf_alloc, int nnz) {
  __shared__ int hist[RPB];
  __shared__ int start[RPB];
  __shared__ int cur[RPB];
  __shared__ int ovf_base;
  __shared__ uint2 out[SORT_CAP];  // 47 KiB
  const int b = blockIdx.x;
  const int t = threadIdx.x;
  const int s = bptr[b];
  const int n = bptr[b + 1] - s;
  const bool ovf = (n > SORT_CAP);

  if (t < RPB) hist[t] = 0;
  __syncthreads();
  for (int i = t; i < n; i += 256)
    atomicAdd(&hist[pairs[s + i].x >> COLBITS], 1);
  __syncthreads();

  // exclusive scan of hist -> start (Hillis-Steele over 128)
  if (t < RPB) start[t] = hist[t];
  __syncthreads();
  for (int off = 1; off < RPB; off <<= 1) {
    int v = 0;
    if (t < RPB && t >= off) v = start[t - off];
    __syncthreads();
    if (t < RPB) start[t] += v;
    __syncthreads();
  }
  if (t < RPB) { start[t] -= hist[t]; cur[t] = start[t]; }
  if (t == 0 && ovf) ovf_base = atomicAdd(ovf_alloc, n);
  __syncthreads();

  // scatter into staged LDS (or global slack if overflow)
  for (int i = t; i < n; i += 256) {
    uint2 p = pairs[s + i];
    int r = (int)(p.x >> COLBITS);
    int pos = atomicAdd(&cur[r], 1);
    uint2 v = make_uint2(p.x & CMASK, p.y);
    if (!ovf) out[pos] = v;
    else pairs[nnz + ovf_base + pos] = v;
  }
  __syncthreads();

  // write back in place (all reads of pairs[s..s+n) completed before this)
  if (!ovf)
    for (int i = t; i < n; i += 256) pairs[s + i] = out[i];

  // per-row segment pointers
  if (t < RPB) {
    int row = b * RPB + t;
    if (row < NNODES) {
      int base = ovf ? (nnz + ovf_base) : s;
      rs[row] = base + start[t];
      re[row] = base + start[t] + hist[t];
    }
  }
}

// Z = e0 (float4 streaming copy from the two split tables).
__global__ void init_Z(const float4* __restrict__ user4,
                       const float4* __restrict__ item4,
                       float4* __restrict__ Z4) {
  const int n4 = NNODES * EMB / 4;
  const int u4 = NUSERS * EMB / 4;
  int i = blockIdx.x * blockDim.x + threadIdx.x;
  if (i >= n4) return;
  Z4[i] = (i < u4) ? user4[i] : item4[i - u4];
}

// ---------------- fused SpMM: dest[r] = scale * (e0[r] + sum val*Z[col]) ----------------
// R5: 4 rows per wave. 16-lane group per row, float4 per lane (16B, full EMB=64).
// One VMEM instruction gathers 4 nnz (one per row-group) -> 4x MLP vs 1 row/wave.
// Register accumulation, no atomics. Pairs loads nontemporal (read-once stream).
__global__ __launch_bounds__(256) void spmm_fused(
    const int* __restrict__ rs, const int* __restrict__ re,
    const uint2* __restrict__ pairs, const float* __restrict__ Z,
    const float* __restrict__ user_emb, const float* __restrict__ item_emb,
    float* __restrict__ dest, float scale) {
  const int lane = threadIdx.x & 63;
  const int sub  = lane >> 4;   // row-group 0..3 within the wave
  const int l4   = lane & 15;   // float4 index within the row (16 x 16B = 256B)
  const int wid  = (int)((blockIdx.x * blockDim.x + threadIdx.x) >> 6);
  const int r = wid * 4 + sub;
  if (r >= NNODES) return;
  const int s = rs[r];
  const int e = re[r];
  const float4* __restrict__ Z4 = (const float4*)Z;
  const unsigned long long* __restrict__ pq = (const unsigned long long*)pairs;

  float4 a0 = make_float4(0.f, 0.f, 0.f, 0.f);
  float4 a1 = make_float4(0.f, 0.f, 0.f, 0.f);
  float4 a2 = make_float4(0.f, 0.f, 0.f, 0.f);
  float4 a3 = make_float4(0.f, 0.f, 0.f, 0.f);

  int i = s;
  for (; i + 3 < e; i += 4) {
    unsigned long long q0 = __builtin_nontemporal_load(&pq[i + 0]);
    unsigned long long q1 = __builtin_nontemporal_load(&pq[i + 1]);
    unsigned long long q2 = __builtin_nontemporal_load(&pq[i + 2]);
    unsigned long long q3 = __builtin_nontemporal_load(&pq[i + 3]);
    unsigned c0 = (unsigned)q0, c1 = (unsigned)q1;
    unsigned c2 = (unsigned)q2, c3 = (unsigned)q3;
    float4 z0 = Z4[(size_t)c0 * 16 + l4];
    float4 z1 = Z4[(size_t)c1 * 16 + l4];
    float4 z2 = Z4[(size_t)c2 * 16 + l4];
    float4 z3 = Z4[(size_t)c3 * 16 + l4];
    float v0 = __uint_as_float((unsigned)(q0 >> 32));
    float v1 = __uint_as_float((unsigned)(q1 >> 32));
    float v2 = __uint_as_float((unsigned)(q2 >> 32));
    float v3 = __uint_as_float((unsigned)(q3 >> 32));
    a0.x = fmaf(v0, z0.x, a0.x); a0.y = fmaf(v0, z0.y, a0.y);
    a0.z = fmaf(v0, z0.z, a0.z); a0.w = fmaf(v0, z0.w, a0.w);
    a1.x = fmaf(v1, z1.x, a1.x); a1.y = fmaf(v1, z1.y, a1.y);
    a1.z = fmaf(v1, z1.z, a1.z); a1.w = fmaf(v1, z1.w, a1.w);
    a2.x = fmaf(v2, z2.x, a2.x); a2.y = fmaf(v2, z2.y, a2.y);
    a2.z = fmaf(v2, z2.z, a2.z); a2.w = fmaf(v2, z2.w, a2.w);
    a3.x = fmaf(v3, z3.x, a3.x); a3.y = fmaf(v3, z3.y, a3.y);
    a3.z = fmaf(v3, z3.z, a3.z); a3.w = fmaf(v3, z3.w, a3.w);
  }
  for (; i < e; ++i) {
    unsigned long long q = __builtin_nontemporal_load(&pq[i]);
    float4 z = Z4[(size_t)(unsigned)q * 16 + l4];
    float v = __uint_as_float((unsigned)(q >> 32));
    a0.x = fmaf(v, z.x, a0.x); a0.y = fmaf(v, z.y, a0.y);
    a0.z = fmaf(v, z.z, a0.z); a0.w = fmaf(v, z.w, a0.w);
  }

  float4 acc;
  acc.x = (a0.x + a1.x) + (a2.x + a3.x);
  acc.y = (a0.y + a1.y) + (a2.y + a3.y);
  acc.z = (a0.z + a1.z) + (a2.z + a3.z);
  acc.w = (a0.w + a1.w) + (a2.w + a3.w);

  const float* __restrict__ esrc =
      (r < NUSERS) ? &user_emb[(size_t)r * EMB]
                   : &item_emb[(size_t)(r - NUSERS) * EMB];
  float4 e0v = ((const float4*)esrc)[l4];
  float4 o;
  o.x = scale * (e0v.x + acc.x);
  o.y = scale * (e0v.y + acc.y);
  o.z = scale * (e0v.z + acc.z);
  o.w = scale * (e0v.w + acc.w);
  ((float4*)dest)[(size_t)r * 16 + l4] = o;
}

// ---------------- fallback (R1 atomic path) ----------------

__global__ void spmm_atomic(const float* __restrict__ vals,
                            const int* __restrict__ rows,
                            const int* __restrict__ cols,
                            const float* __restrict__ user_emb,
                            const float* __restrict__ item_emb,
                            const float* __restrict__ prev, int nnz,
                            float* __restrict__ y) {
  const int lane = threadIdx.x & 63;
  int wave = (int)((blockIdx.x * blockDim.x + threadIdx.x) >> 6);
  const int nwaves = (int)((gridDim.x * blockDim.x) >> 6);
  for (int nz = wave; nz < nnz; nz += nwaves) {
    float v = vals[nz];
    int r = rows[nz];
    int c = cols[nz];
    float xv = (c < NUSERS) ? user_emb[(size_t)c * EMB + lane]
                            : item_emb[(size_t)(c - NUSERS) * EMB + lane];
    if (prev) xv += prev[(size_t)c * EMB + lane];
    atomicAdd(&y[(size_t)r * EMB + lane], v * xv);
  }
}

__global__ void finalize_kernel(const float4* __restrict__ user4,
                                const float4* __restrict__ item4,
                                float4* __restrict__ X4) {
  const int n4 = NNODES * EMB / 4;
  const int u4 = NUSERS * EMB / 4;
  int i = blockIdx.x * blockDim.x + threadIdx.x;
  if (i >= n4) return;
  float4 a = (i < u4) ? user4[i] : item4[i - u4];
  float4 b = X4[i];
  b.x = 0.25f * (a.x + b.x);
  b.y = 0.25f * (a.y + b.y);
  b.z = 0.25f * (a.z + b.z);
  b.w = 0.25f * (a.w + b.w);
  X4[i] = b;
}

// ---------------- launch ----------------

extern "C" void kernel_launch(void* const* d_in, const int* in_sizes, int n_in,
                              void* d_out, int out_size, void* d_ws, size_t ws_size,
                              hipStream_t stream) {
  const float* user_emb = (const float*)d_in[0];
  const float* item_emb = (const float*)d_in[1];
  const float* vals     = (const float*)d_in[2];
  const int*   rows     = (const int*)d_in[3];
  const int*   cols     = (const int*)d_in[4];
  const int nnz = in_sizes[2];
  float* W = (float*)d_out;  // ping-pong partner

  const float4* user4 = (const float4*)user_emb;
  const float4* item4 = (const float4*)item_emb;

  const size_t embBytes  = (size_t)NNODES * EMB * sizeof(float);          // 128 MB
  const size_t pairBytes = ((size_t)nnz + SLACK_PAIRS) * sizeof(uint2);   // ~81 MB
  const size_t rsBytes   = ((size_t)NNODES * 4 + 255) & ~(size_t)255;     // 2 MB
  const size_t reBytes   = rsBytes;
  const size_t ptrBytes  = ((size_t)(NBUCKETS + 1) * 4 + 255) & ~(size_t)255;
  const size_t curBytes  = ((size_t)NBUCKETS * 4 + 255) & ~(size_t)255;
  const size_t cntBytes  = ((size_t)NBUCKETS * 4 + 255) & ~(size_t)255;
  const size_t ovfBytes  = 256;
  const size_t need = embBytes + pairBytes + rsBytes + reBytes + ptrBytes +
                      curBytes + cntBytes + ovfBytes;

  dim3 blk(256);

  if (ws_size < need) {  // safety fallback: R1 atomic path (128 MB ws)
    float* Y = (float*)d_ws;
    hipMemsetAsync(W, 0, embBytes, stream);
    hipMemsetAsync(Y, 0, embBytes, stream);
    dim3 grid(4096);
    spmm_atomic<<<grid, blk, 0, stream>>>(vals, rows, cols, user_emb, item_emb, nullptr, nnz, W);
    spmm_atomic<<<grid, blk, 0, stream>>>(vals, rows, cols, user_emb, item_emb, W, nnz, Y);
    hipMemsetAsync(W, 0, embBytes, stream);
    spmm_atomic<<<grid, blk, 0, stream>>>(vals, rows, cols, user_emb, item_emb, Y, nnz, W);
    const int n4 = NNODES * EMB / 4;
    finalize_kernel<<<(n4 + 255) / 256, blk, 0, stream>>>(user4, item4, (float4*)W);
    return;
  }

  char* ws = (char*)d_ws;
  float* Z      = (float*)ws;  ws += embBytes;
  uint2* pairs  = (uint2*)ws;  ws += pairBytes;
  int*   rsArr  = (int*)ws;    ws += rsBytes;
  int*   reArr  = (int*)ws;    ws += reBytes;
  int*   bptr   = (int*)ws;    ws += ptrBytes;
  int*   cursor = (int*)ws;    ws += curBytes;
  int*   counts = (int*)ws;    ws += cntBytes;
  int*   ovf    = (int*)ws;

  // --- bucket + sort the COO ---
  hipMemsetAsync(counts, 0, (size_t)NBUCKETS * 4, stream);
  hipMemsetAsync(ovf, 0, 4, stream);
  hist_bucket<<<256, blk, 0, stream>>>(rows, nnz, counts);
  scan_buckets<<<1, 512, 0, stream>>>(counts, bptr, cursor, NBUCKETS, nnz);
  scatter_bucket<<<1024, blk, 0, stream>>>(rows, cols, vals, nnz, cursor, pairs);
  sort_bucket<<<NBUCKETS, 256, 0, stream>>>(bptr, pairs, rsArr, reArr, ovf, nnz);

  // --- Z = e0 ---
  const int n4 = NNODES * EMB / 4;
  init_Z<<<(n4 + 255) / 256, blk, 0, stream>>>(user4, item4, (float4*)Z);

  // --- 3 layers, Horner ping-pong, fused epilogue ---
  // 4 rows per wave, 4 waves per block -> 16 rows per block.
  const int sgrid = NNODES / 16;  // 31250
  spmm_fused<<<sgrid, blk, 0, stream>>>(rsArr, reArr, pairs, Z, user_emb, item_emb, W, 1.0f);
  spmm_fused<<<sgrid, blk, 0, stream>>>(rsArr, reArr, pairs, W, user_emb, item_emb, Z, 1.0f);
  spmm_fused<<<sgrid, blk, 0, stream>>>(rsArr, reArr, pairs, Z, user_emb, item_emb, W, 0.25f);
}

// Round 3
// 1849.709 us; speedup vs baseline: 1.2614x; 1.2614x over previous
//
#include <hip/hip_runtime.h>

// LightGCN: out = 0.25*(e0 + S e0 + S^2 e0 + S^3 e0), S = 10M-nnz COO, N=500k, EMB=64.
// R4: bucket scatter + LDS counting sort + 3x register SpMM. 2572.6 us.
// R5/R6: spmm 4 rows/wave (16 lanes x float4), nontemporal pairs. 2333.2 us.
//   rocprof: scatter_bucket = 699us, WRITE_SIZE 563MB (7x amp: random 8B writes
//   dirty full 64B lines at 915 GB/s random-line write ceiling).
// R7: two-pass aggregated scatter replaces scatter_bucket + sort_bucket:
//   Pass 1 (scatter_sb): per-block 7168-pair tile binned by 489 super-buckets
//     (1024 rows each) in LDS, one global atomic per SB per tile, coalesced
//     ~117B segment writes -> write amp ~1.5 instead of 8.
//   Pass 2 (finalize_sb): one 1024-thread block per SB; loads the whole ~160KB
//     SB region into registers (24 pairs/thread), LDS counting sort by row,
//     writes rs/re, scatters in place (barrier between all reads and all
//     writes; dest window L2-resident so writebacks are full lines).
// Horner ping-pong (Z in ws, W = d_out):
//   Z=e0; L1: W = e0 + S Z; L2: Z = e0 + S W; L3: out = 0.25*(e0 + S Z).

#define NUSERS 100000
#define NNODES 500000
#define EMB 64
#define COLBITS 19
#define CMASK ((1u << COLBITS) - 1u)

#define SBBITS 10                                  // 1024 rows per super-bucket
#define SBROWS (1 << SBBITS)
#define SBMASK (SBROWS - 1)
#define NSB ((NNODES + SBROWS - 1) / SBROWS)       // 489
#define TILE 7168                                  // pairs staged per block in pass 1
#define P2_THREADS 1024
#define P2_K 24                                    // pairs/thread in pass 2 (cap 24576; mean 20480, sd ~143)
#define P2_CAP (P2_THREADS * P2_K)
#define SLACK_PAIRS 262144                         // pass-2 overflow staging (never hit for random rows)

// ---------------- preprocessing ----------------

// Per-super-bucket histogram (LDS-combined).
__global__ void hist_sb(const int* __restrict__ rows, int nnz,
                        int* __restrict__ counts) {
  __shared__ int h[NSB];
  for (int i = threadIdx.x; i < NSB; i += blockDim.x) h[i] = 0;
  __syncthreads();
  int i = blockIdx.x * blockDim.x + threadIdx.x;
  int stride = gridDim.x * blockDim.x;
  for (; i < nnz; i += stride) atomicAdd(&h[rows[i] >> SBBITS], 1);
  __syncthreads();
  for (int j = threadIdx.x; j < NSB; j += blockDim.x)
    if (h[j]) atomicAdd(&counts[j], h[j]);
}

// Single-block exclusive scan of counts[n] (n <= 4096), 512 threads x 8.
__global__ void scan_buckets(const int* __restrict__ counts,
                             int* __restrict__ bptr, int* __restrict__ cursor,
                             int n, int nnz) {
  __shared__ int s[512];
  const int t = threadIdx.x;
  const int base = t * 8;
  int e[8];
  int tsum = 0;
#pragma unroll
  for (int j = 0; j < 8; ++j) {
    e[j] = (base + j < n) ? counts[base + j] : 0;
    tsum += e[j];
  }
  s[t] = tsum;
  __syncthreads();
  for (int off = 1; off < 512; off <<= 1) {
    int v = (t >= off) ? s[t - off] : 0;
    __syncthreads();
    s[t] += v;
    __syncthreads();
  }
  int run = s[t] - tsum;
#pragma unroll
  for (int j = 0; j < 8; ++j) {
    if (base + j < n) { bptr[base + j] = run; cursor[base + j] = run; }
    run += e[j];
  }
  if (t == 511) bptr[n] = nnz;
}

// Pass 1: LDS-aggregated scatter into NSB super-bucket regions.
// One block = one tile of TILE pairs. key = (row&1023)<<19 | col, val alongside.
__global__ __launch_bounds__(256) void scatter_sb(
    const int* __restrict__ rows, const int* __restrict__ cols,
    const float* __restrict__ vals, int nnz,
    int* __restrict__ cursor, unsigned long long* __restrict__ pairs) {
  __shared__ unsigned long long stg[TILE];     // 56 KiB
  __shared__ int cnt[NSB];                     // doubles as cur after reserve
  __shared__ int start[NSB];
  __shared__ int sbase[NSB];
  __shared__ int ssc[256];
  const int t = threadIdx.x;
  const int tile0 = blockIdx.x * TILE;
  const int tileN = min(TILE, nnz - tile0);
  if (tileN <= 0) return;

  for (int i = t; i < NSB; i += 256) cnt[i] = 0;
  __syncthreads();

  // phase A: read rows, histogram by SB (rows kept in registers)
  int rr[TILE / 256];
#pragma unroll
  for (int k = 0; k < TILE / 256; ++k) {
    int idx = tile0 + t + k * 256;
    rr[k] = (idx < nnz) ? rows[idx] : -1;
    if (rr[k] >= 0) atomicAdd(&cnt[rr[k] >> SBBITS], 1);
  }
  __syncthreads();

  // exclusive scan of cnt -> start (2 entries/thread, Hillis-Steele over 256)
  {
    const int i0 = 2 * t, i1 = 2 * t + 1;
    int c0 = (i0 < NSB) ? cnt[i0] : 0;
    int c1 = (i1 < NSB) ? cnt[i1] : 0;
    int tsum = c0 + c1;
    ssc[t] = tsum;
    __syncthreads();
    for (int off = 1; off < 256; off <<= 1) {
      int v = (t >= off) ? ssc[t - off] : 0;
      __syncthreads();
      ssc[t] += v;
      __syncthreads();
    }
    int excl = ssc[t] - tsum;
    if (i0 < NSB) start[i0] = excl;
    if (i1 < NSB) start[i1] = excl + c0;
  }
  __syncthreads();

  // reserve global segments (one atomic per non-empty SB), then reset cnt->cur
  for (int sb = t; sb < NSB; sb += 256) {
    int c = cnt[sb];
    if (c) sbase[sb] = atomicAdd(&cursor[sb], c);
  }
  __syncthreads();
  for (int i = t; i < NSB; i += 256) cnt[i] = 0;
  __syncthreads();

  // phase B: read cols/vals, stage pairs grouped by SB in LDS
#pragma unroll
  for (int k = 0; k < TILE / 256; ++k) {
    int idx = tile0 + t + k * 256;
    if (idx < nnz) {
      int r = rr[k];
      int sb = r >> SBBITS;
      unsigned key = ((unsigned)(r & SBMASK) << COLBITS) | (unsigned)cols[idx];
      unsigned long long p =
          ((unsigned long long)__float_as_uint(vals[idx]) << 32) | key;
      int j = start[sb] + atomicAdd(&cnt[sb], 1);
      stg[j] = p;
    }
  }
  __syncthreads();

  // phase C: write staged pairs out; consecutive j -> same SB -> coalesced runs.
  for (int j = t; j < tileN; j += 256) {
    // largest sb with start[sb] <= j
    int lo = 0, hi = NSB - 1;
    while (lo < hi) {
      int mid = (lo + hi + 1) >> 1;
      if (start[mid] <= j) lo = mid; else hi = mid - 1;
    }
    pairs[sbase[lo] + (j - start[lo])] = stg[j];
  }
}

// Pass 2: per-SB row grouping. Loads the SB region into registers, counting
// sort by row in LDS, writes rs/re, scatters in place (reads all before writes).
__global__ __launch_bounds__(P2_THREADS) void finalize_sb(
    const int* __restrict__ bptr, unsigned long long* __restrict__ pairs,
    int* __restrict__ rs, int* __restrict__ re,
    int* __restrict__ ovf_alloc, int nnz) {
  __shared__ int hist[SBROWS];
  __shared__ int start[SBROWS];
  __shared__ int cur[SBROWS];
  __shared__ int ovf_base;
  const int b = blockIdx.x;
  const int t = threadIdx.x;
  const int s = bptr[b];
  const int n = bptr[b + 1] - s;
  const bool ovf = (n > P2_CAP);

  hist[t] = 0;
  unsigned long long* __restrict__ slack = pairs + nnz;
  if (ovf && t == 0) ovf_base = atomicAdd(ovf_alloc, n);
  __syncthreads();

  unsigned long long q[P2_K];
  if (!ovf) {
    // load whole region into registers + histogram rows
#pragma unroll
    for (int k = 0; k < P2_K; ++k) {
      int idx = t + k * P2_THREADS;
      if (idx < n) {
        q[k] = pairs[s + idx];
        atomicAdd(&hist[(unsigned)q[k] >> COLBITS], 1);
      }
    }
  } else {
    // overflow: stage through global slack (copy out, then operate from slack)
    for (int j = t; j < n; j += P2_THREADS) slack[ovf_base + j] = pairs[s + j];
    __syncthreads();
    for (int j = t; j < n; j += P2_THREADS)
      atomicAdd(&hist[(unsigned)slack[ovf_base + j] >> COLBITS], 1);
  }
  __syncthreads();

  // exclusive scan over SBROWS (=P2_THREADS) rows
  start[t] = hist[t];
  __syncthreads();
  for (int off = 1; off < SBROWS; off <<= 1) {
    int v = (t >= off) ? start[t - off] : 0;
    __syncthreads();
    start[t] += v;
    __syncthreads();
  }
  int excl = start[t] - hist[t];
  cur[t] = excl;

  int row = b * SBROWS + t;
  if (row < NNODES) {
    rs[row] = s + excl;
    re[row] = s + excl + hist[t];
  }
  __syncthreads();   // all reads of pairs[s..s+n) done (register path) before writes

  if (!ovf) {
#pragma unroll
    for (int k = 0; k < P2_K; ++k) {
      int idx = t + k * P2_THREADS;
      if (idx < n) {
        unsigned key = (unsigned)q[k];
        int pos = atomicAdd(&cur[key >> COLBITS], 1);
        pairs[s + pos] = ((q[k] >> 32) << 32) | (key & CMASK);
      }
    }
  } else {
    for (int j = t; j < n; j += P2_THREADS) {
      unsigned long long p = slack[ovf_base + j];
      unsigned key = (unsigned)p;
      int pos = atomicAdd(&cur[key >> COLBITS], 1);
      pairs[s + pos] = ((p >> 32) << 32) | (key & CMASK);
    }
  }
}

// Z = e0 (float4 streaming copy from the two split tables).
__global__ void init_Z(const float4* __restrict__ user4,
                       const float4* __restrict__ item4,
                       float4* __restrict__ Z4) {
  const int n4 = NNODES * EMB / 4;
  const int u4 = NUSERS * EMB / 4;
  int i = blockIdx.x * blockDim.x + threadIdx.x;
  if (i >= n4) return;
  Z4[i] = (i < u4) ? user4[i] : item4[i - u4];
}

// ---------------- fused SpMM: dest[r] = scale * (e0[r] + sum val*Z[col]) ----------------
// 4 rows per wave, 16-lane group per row, float4 per lane. Register accumulation.
__global__ __launch_bounds__(256) void spmm_fused(
    const int* __restrict__ rs, const int* __restrict__ re,
    const unsigned long long* __restrict__ pq, const float* __restrict__ Z,
    const float* __restrict__ user_emb, const float* __restrict__ item_emb,
    float* __restrict__ dest, float scale) {
  const int lane = threadIdx.x & 63;
  const int sub  = lane >> 4;   // row-group 0..3 within the wave
  const int l4   = lane & 15;   // float4 index within the row
  const int wid  = (int)((blockIdx.x * blockDim.x + threadIdx.x) >> 6);
  const int r = wid * 4 + sub;
  if (r >= NNODES) return;
  const int s = rs[r];
  const int e = re[r];
  const float4* __restrict__ Z4 = (const float4*)Z;

  float4 a0 = make_float4(0.f, 0.f, 0.f, 0.f);
  float4 a1 = make_float4(0.f, 0.f, 0.f, 0.f);
  float4 a2 = make_float4(0.f, 0.f, 0.f, 0.f);
  float4 a3 = make_float4(0.f, 0.f, 0.f, 0.f);

  int i = s;
  for (; i + 3 < e; i += 4) {
    unsigned long long q0 = __builtin_nontemporal_load(&pq[i + 0]);
    unsigned long long q1 = __builtin_nontemporal_load(&pq[i + 1]);
    unsigned long long q2 = __builtin_nontemporal_load(&pq[i + 2]);
    unsigned long long q3 = __builtin_nontemporal_load(&pq[i + 3]);
    unsigned c0 = (unsigned)q0, c1 = (unsigned)q1;
    unsigned c2 = (unsigned)q2, c3 = (unsigned)q3;
    float4 z0 = Z4[(size_t)c0 * 16 + l4];
    float4 z1 = Z4[(size_t)c1 * 16 + l4];
    float4 z2 = Z4[(size_t)c2 * 16 + l4];
    float4 z3 = Z4[(size_t)c3 * 16 + l4];
    float v0 = __uint_as_float((unsigned)(q0 >> 32));
    float v1 = __uint_as_float((unsigned)(q1 >> 32));
    float v2 = __uint_as_float((unsigned)(q2 >> 32));
    float v3 = __uint_as_float((unsigned)(q3 >> 32));
    a0.x = fmaf(v0, z0.x, a0.x); a0.y = fmaf(v0, z0.y, a0.y);
    a0.z = fmaf(v0, z0.z, a0.z); a0.w = fmaf(v0, z0.w, a0.w);
    a1.x = fmaf(v1, z1.x, a1.x); a1.y = fmaf(v1, z1.y, a1.y);
    a1.z = fmaf(v1, z1.z, a1.z); a1.w = fmaf(v1, z1.w, a1.w);
    a2.x = fmaf(v2, z2.x, a2.x); a2.y = fmaf(v2, z2.y, a2.y);
    a2.z = fmaf(v2, z2.z, a2.z); a2.w = fmaf(v2, z2.w, a2.w);
    a3.x = fmaf(v3, z3.x, a3.x); a3.y = fmaf(v3, z3.y, a3.y);
    a3.z = fmaf(v3, z3.z, a3.z); a3.w = fmaf(v3, z3.w, a3.w);
  }
  for (; i < e; ++i) {
    unsigned long long q = __builtin_nontemporal_load(&pq[i]);
    float4 z = Z4[(size_t)(unsigned)q * 16 + l4];
    float v = __uint_as_float((unsigned)(q >> 32));
    a0.x = fmaf(v, z.x, a0.x); a0.y = fmaf(v, z.y, a0.y);
    a0.z = fmaf(v, z.z, a0.z); a0.w = fmaf(v, z.w, a0.w);
  }

  float4 acc;
  acc.x = (a0.x + a1.x) + (a2.x + a3.x);
  acc.y = (a0.y + a1.y) + (a2.y + a3.y);
  acc.z = (a0.z + a1.z) + (a2.z + a3.z);
  acc.w = (a0.w + a1.w) + (a2.w + a3.w);

  const float* __restrict__ esrc =
      (r < NUSERS) ? &user_emb[(size_t)r * EMB]
                   : &item_emb[(size_t)(r - NUSERS) * EMB];
  float4 e0v = ((const float4*)esrc)[l4];
  float4 o;
  o.x = scale * (e0v.x + acc.x);
  o.y = scale * (e0v.y + acc.y);
  o.z = scale * (e0v.z + acc.z);
  o.w = scale * (e0v.w + acc.w);
  ((float4*)dest)[(size_t)r * 16 + l4] = o;
}

// ---------------- fallback (atomic path, correct for any ws size) ----------------

__global__ void spmm_atomic(const float* __restrict__ vals,
                            const int* __restrict__ rows,
                            const int* __restrict__ cols,
                            const float* __restrict__ user_emb,
                            const float* __restrict__ item_emb,
                            const float* __restrict__ prev, int nnz,
                            float* __restrict__ y) {
  const int lane = threadIdx.x & 63;
  int wave = (int)((blockIdx.x * blockDim.x + threadIdx.x) >> 6);
  const int nwaves = (int)((gridDim.x * blockDim.x) >> 6);
  for (int nz = wave; nz < nnz; nz += nwaves) {
    float v = vals[nz];
    int r = rows[nz];
    int c = cols[nz];
    float xv = (c < NUSERS) ? user_emb[(size_t)c * EMB + lane]
                            : item_emb[(size_t)(c - NUSERS) * EMB + lane];
    if (prev) xv += prev[(size_t)c * EMB + lane];
    atomicAdd(&y[(size_t)r * EMB + lane], v * xv);
  }
}

__global__ void finalize_kernel(const float4* __restrict__ user4,
                                const float4* __restrict__ item4,
                                float4* __restrict__ X4) {
  const int n4 = NNODES * EMB / 4;
  const int u4 = NUSERS * EMB / 4;
  int i = blockIdx.x * blockDim.x + threadIdx.x;
  if (i >= n4) return;
  float4 a = (i < u4) ? user4[i] : item4[i - u4];
  float4 b = X4[i];
  b.x = 0.25f * (a.x + b.x);
  b.y = 0.25f * (a.y + b.y);
  b.z = 0.25f * (a.z + b.z);
  b.w = 0.25f * (a.w + b.w);
  X4[i] = b;
}

// ---------------- launch ----------------

extern "C" void kernel_launch(void* const* d_in, const int* in_sizes, int n_in,
                              void* d_out, int out_size, void* d_ws, size_t ws_size,
                              hipStream_t stream) {
  const float* user_emb = (const float*)d_in[0];
  const float* item_emb = (const float*)d_in[1];
  const float* vals     = (const float*)d_in[2];
  const int*   rows     = (const int*)d_in[3];
  const int*   cols     = (const int*)d_in[4];
  const int nnz = in_sizes[2];
  float* W = (float*)d_out;  // ping-pong partner

  const float4* user4 = (const float4*)user_emb;
  const float4* item4 = (const float4*)item_emb;

  const size_t embBytes  = (size_t)NNODES * EMB * sizeof(float);            // 128 MB
  const size_t pairBytes = ((size_t)nnz + SLACK_PAIRS) * sizeof(uint2);     // ~82 MB
  const size_t rsBytes   = ((size_t)NNODES * 4 + 255) & ~(size_t)255;       // 2 MB
  const size_t reBytes   = rsBytes;
  const size_t ptrBytes  = ((size_t)(NSB + 1) * 4 + 255) & ~(size_t)255;
  const size_t curBytes  = ((size_t)NSB * 4 + 255) & ~(size_t)255;
  const size_t cntBytes  = ((size_t)NSB * 4 + 255) & ~(size_t)255;
  const size_t ovfBytes  = 256;
  const size_t need = embBytes + pairBytes + rsBytes + reBytes + ptrBytes +
                      curBytes + cntBytes + ovfBytes;

  dim3 blk(256);

  if (ws_size < need) {  // safety fallback: atomic path (128 MB ws)
    float* Y = (float*)d_ws;
    hipMemsetAsync(W, 0, embBytes, stream);
    hipMemsetAsync(Y, 0, embBytes, stream);
    dim3 grid(4096);
    spmm_atomic<<<grid, blk, 0, stream>>>(vals, rows, cols, user_emb, item_emb, nullptr, nnz, W);
    spmm_atomic<<<grid, blk, 0, stream>>>(vals, rows, cols, user_emb, item_emb, W, nnz, Y);
    hipMemsetAsync(W, 0, embBytes, stream);
    spmm_atomic<<<grid, blk, 0, stream>>>(vals, rows, cols, user_emb, item_emb, Y, nnz, W);
    const int n4 = NNODES * EMB / 4;
    finalize_kernel<<<(n4 + 255) / 256, blk, 0, stream>>>(user4, item4, (float4*)W);
    return;
  }

  char* ws = (char*)d_ws;
  float* Z      = (float*)ws;  ws += embBytes;
  unsigned long long* pairs = (unsigned long long*)ws;  ws += pairBytes;
  int*   rsArr  = (int*)ws;    ws += rsBytes;
  int*   reArr  = (int*)ws;    ws += reBytes;
  int*   bptr   = (int*)ws;    ws += ptrBytes;
  int*   cursor = (int*)ws;    ws += curBytes;
  int*   counts = (int*)ws;    ws += cntBytes;
  int*   ovf    = (int*)ws;

  // --- two-pass aggregated bucket/sort of the COO ---
  hipMemsetAsync(counts, 0, (size_t)NSB * 4, stream);
  hipMemsetAsync(ovf, 0, 4, stream);
  hist_sb<<<256, blk, 0, stream>>>(rows, nnz, counts);
  scan_buckets<<<1, 512, 0, stream>>>(counts, bptr, cursor, NSB, nnz);
  const int ntiles = (nnz + TILE - 1) / TILE;
  scatter_sb<<<ntiles, blk, 0, stream>>>(rows, cols, vals, nnz, cursor, pairs);
  finalize_sb<<<NSB, P2_THREADS, 0, stream>>>(bptr, pairs, rsArr, reArr, ovf, nnz);

  // --- Z = e0 ---
  const int n4 = NNODES * EMB / 4;
  init_Z<<<(n4 + 255) / 256, blk, 0, stream>>>(user4, item4, (float4*)Z);

  // --- 3 layers, Horner ping-pong, fused epilogue ---
  const int sgrid = NNODES / 16;  // 31250 blocks; 4 rows/wave, 16 rows/block
  spmm_fused<<<sgrid, blk, 0, stream>>>(rsArr, reArr, pairs, Z, user_emb, item_emb, W, 1.0f);
  spmm_fused<<<sgrid, blk, 0, stream>>>(rsArr, reArr, pairs, W, user_emb, item_emb, Z, 1.0f);
  spmm_fused<<<sgrid, blk, 0, stream>>>(rsArr, reArr, pairs, Z, user_emb, item_emb, W, 0.25f);
}